// Round 2
// baseline (246.056 us; speedup 1.0000x reference)
//
#include <hip/hip_runtime.h>
#include <math.h>

typedef _Float16 h2 __attribute__((ext_vector_type(2)));
typedef _Float16 h4 __attribute__((ext_vector_type(4)));
typedef _Float16 h8 __attribute__((ext_vector_type(8)));

#define NEG_SLOPE 0.2f
#define LN_EPS 1e-5f
#define RESCALE_THR 8.0f

// ---------------- K0: zero deg/cursor/easum ----------------
__global__ void init_kernel(int* __restrict__ deg, int* __restrict__ cursor,
                            float* __restrict__ easum, int n) {
    int i = blockIdx.x * 256 + threadIdx.x;
    if (i < n) { deg[i] = 0; cursor[i] = 0; }
    if (i == 0) easum[0] = 0.f;
}

// ---------------- K1: x_l = x@Wl+bl, x_r = x@Wr+br -> fp16 ----------------
__global__ __launch_bounds__(256) void transform_kernel(
    const float* __restrict__ x, const float* __restrict__ Wl, const float* __restrict__ bl,
    const float* __restrict__ Wr, const float* __restrict__ br,
    _Float16* __restrict__ xlh, _Float16* __restrict__ xrh, int n) {
    __shared__ float xs[8][64];
    int nb = blockIdx.x * 8;
    int rows = n - nb; if (rows > 8) rows = 8;
    int t = threadIdx.x;
    for (int i = t; i < rows * 64; i += 256) xs[i >> 6][i & 63] = x[(size_t)nb * 64 + i];
    __syncthreads();
    float blv = bl[t], brv = br[t];
    float accl[8], accr[8];
#pragma unroll
    for (int i = 0; i < 8; ++i) { accl[i] = blv; accr[i] = brv; }
    for (int k = 0; k < 64; k += 4) {
        float wl0 = Wl[(k + 0) * 256 + t], wl1 = Wl[(k + 1) * 256 + t];
        float wl2 = Wl[(k + 2) * 256 + t], wl3 = Wl[(k + 3) * 256 + t];
        float wr0 = Wr[(k + 0) * 256 + t], wr1 = Wr[(k + 1) * 256 + t];
        float wr2 = Wr[(k + 2) * 256 + t], wr3 = Wr[(k + 3) * 256 + t];
#pragma unroll
        for (int i = 0; i < 8; ++i) {
            float4 xv = *(const float4*)&xs[i][k];   // broadcast read, conflict-free
            accl[i] += xv.x * wl0 + xv.y * wl1 + xv.z * wl2 + xv.w * wl3;
            accr[i] += xv.x * wr0 + xv.y * wr1 + xv.z * wr2 + xv.w * wr3;
        }
    }
    for (int i = 0; i < rows; ++i) {
        xlh[(size_t)(nb + i) * 256 + t] = (_Float16)accl[i];
        xrh[(size_t)(nb + i) * 256 + t] = (_Float16)accr[i];
    }
}

// ---------------- K2: in-degree count + edge_attr sum ----------------
__global__ void edge_prep(const int* __restrict__ ei, const float* __restrict__ ea,
                          int* __restrict__ deg, float* __restrict__ easum, int E) {
    int i = blockIdx.x * 256 + threadIdx.x;
    float s = 0.f;
    if (i < E) { atomicAdd(&deg[ei[E + i]], 1); s = ea[i]; }
#pragma unroll
    for (int o = 32; o >= 1; o >>= 1) s += __shfl_xor(s, o);
    if ((threadIdx.x & 63) == 0) atomicAdd(easum, s);
}

// ---------------- K3: exclusive scan deg -> off ----------------
__global__ __launch_bounds__(256) void scan_kernel(const int* __restrict__ deg,
                                                   int* __restrict__ off, int n) {
    __shared__ int part[256];
    int t = threadIdx.x;
    int C = (n + 255) / 256;
    int lo = t * C; if (lo > n) lo = n;
    int hi = lo + C; if (hi > n) hi = n;
    int s = 0;
    for (int i = lo; i < hi; ++i) s += deg[i];
    part[t] = s;
    __syncthreads();
    for (int d = 1; d < 256; d <<= 1) {
        int v = part[t];
        int u = (t >= d) ? part[t - d] : 0;
        __syncthreads();
        part[t] = v + u;
        __syncthreads();
    }
    int base = (t > 0) ? part[t - 1] : 0;
    for (int i = lo; i < hi; ++i) { off[i] = base; base += deg[i]; }
    if (t == 255) off[n] = part[255];
}

// ---------------- K4: fill CSR ----------------
__global__ void fill_kernel(const int* __restrict__ ei, const float* __restrict__ ea,
                            const int* __restrict__ off, int* __restrict__ cursor,
                            int* __restrict__ csr_src, float* __restrict__ csr_ea, int E) {
    int i = blockIdx.x * 256 + threadIdx.x;
    if (i < E) {
        int d = ei[E + i];
        int pos = atomicAdd(&cursor[d], 1);
        int idx = off[d] + pos;
        csr_src[idx] = ei[i];
        csr_ea[idx] = ea[i];
    }
}

// ---------------- K5: per-node GATv2, two edges in flight (half-wave each) ----------------
__global__ __launch_bounds__(256) void gat_kernel(
    const _Float16* __restrict__ xlh, const _Float16* __restrict__ xrh,
    const int* __restrict__ off, const int* __restrict__ csr_src, const float* __restrict__ csr_ea,
    const float* __restrict__ att, const float* __restrict__ We, const float* __restrict__ bias_conv,
    const float* __restrict__ easum, _Float16* __restrict__ hg, int n, float inv_e) {
    int wid = (blockIdx.x * blockDim.x + threadIdx.x) >> 6;
    if (wid >= n) return;
    int lane = threadIdx.x & 63;
    int half = lane >> 5, s = lane & 31;      // lane covers dims 8s..8s+7
    float ea_mean = easum[0] * inv_e;

    h8 xrv = ((const h8*)xrh)[(size_t)wid * 32 + s];
    h2 xr2[4], we2[4], c02 = {(_Float16)NEG_SLOPE, (_Float16)NEG_SLOPE};
    float atf[8];
    const float* attp = att + 8 * s;
    const float* wep = We + 8 * s;
#pragma unroll
    for (int j = 0; j < 4; ++j) {
        xr2[j] = (h2){xrv[2 * j], xrv[2 * j + 1]};
        we2[j] = (h2){(_Float16)wep[2 * j], (_Float16)wep[2 * j + 1]};
        atf[2 * j] = attp[2 * j]; atf[2 * j + 1] = attp[2 * j + 1];
    }
    const h8* xl8 = (const h8*)xlh;

    float M = -1e30f, S = 0.f, acc[8];
#pragma unroll
    for (int j = 0; j < 8; ++j) acc[j] = 0.f;
    int e0 = off[wid];
    int total = off[wid + 1] - e0 + 1;        // +1 = self loop at i==0

    auto edge_compute = [&](int i, float* vf) -> float {
        int src; float a;
        if (i == 0) { src = wid; a = ea_mean; }
        else        { src = csr_src[e0 + i - 1]; a = csr_ea[e0 + i - 1]; }
        h8 v = xl8[(size_t)src * 32 + s];
        _Float16 ah = (_Float16)a;
        h2 aa = {ah, ah};
        float p = 0.f;
#pragma unroll
        for (int j = 0; j < 4; ++j) {
            h2 vj = (h2){v[2 * j], v[2 * j + 1]};
            h2 m = aa * we2[j] + (vj + xr2[j]);
            h2 l = __builtin_elementwise_max(m, m * c02);   // leaky relu
            p += (float)l[0] * atf[2 * j] + (float)l[1] * atf[2 * j + 1];
            vf[2 * j] = (float)vj[0]; vf[2 * j + 1] = (float)vj[1];
        }
        // reduce over the 8 sublanes of this head (lane bits 0..2)
        p += __shfl_xor(p, 1);
        p += __shfl_xor(p, 2);
        p += __shfl_xor(p, 4);
        return p;
    };

    int i = half;
    if (i < total) {                  // first edge of this half: init state
        float vf[8];
        float p = edge_compute(i, vf);
        M = p; S = 1.f;
#pragma unroll
        for (int j = 0; j < 8; ++j) acc[j] = vf[j];
        i += 2;
    }
    for (; i < total; i += 2) {
        float vf[8];
        float p = edge_compute(i, vf);
        if (__all(p <= M + RESCALE_THR)) {     // defer-max fast path (wave-uniform)
            float w = __expf(p - M);
            S += w;
#pragma unroll
            for (int j = 0; j < 8; ++j) acc[j] += w * vf[j];
        } else {
            float newM = fmaxf(M, p);
            float sc = __expf(M - newM), w = __expf(p - newM);
            S = S * sc + w;
#pragma unroll
            for (int j = 0; j < 8; ++j) acc[j] = acc[j] * sc + w * vf[j];
            M = newM;
        }
    }

    // merge the two half-wave softmax states
    float Mo = __shfl_xor(M, 32);
    float newM = fmaxf(M, Mo);
    float sc = __expf(M - newM);
    S *= sc;
    S += __shfl_xor(S, 32);
#pragma unroll
    for (int j = 0; j < 8; ++j) { acc[j] *= sc; acc[j] += __shfl_xor(acc[j], 32); }
    float inv = 1.f / (S + 1e-16f);

    float4 bc = ((const float4*)bias_conv)[2 * s + half];
    const float* ap = acc + 4 * half;
    h4 ov = {(_Float16)(ap[0] * inv + bc.x), (_Float16)(ap[1] * inv + bc.y),
             (_Float16)(ap[2] * inv + bc.z), (_Float16)(ap[3] * inv + bc.w)};
    ((h4*)hg)[(size_t)wid * 64 + 2 * s + half] = ov;
}

// ---------------- K6: proj(256->64) + residual + ELU + LN, 64-node tile ----------------
__global__ __launch_bounds__(256) void proj_ln_kernel(
    const _Float16* __restrict__ hg, const float* __restrict__ Wp, const float* __restrict__ bp,
    const float* __restrict__ x, const float* __restrict__ gamma, const float* __restrict__ beta,
    float* __restrict__ out, int n) {
    __shared__ float wp_s[256 * 64];     // 64 KB
    __shared__ float hs[64][260];        // padded stride: kills bank aliasing
    int t = threadIdx.x;
    int nb = blockIdx.x * 64;
    for (int idx = t; idx < 4096; idx += 256)
        ((float4*)wp_s)[idx] = ((const float4*)Wp)[idx];
    for (int idx = t; idx < 2048; idx += 256) {
        int row = idx >> 5, c8 = idx & 31;
        h8 hv = (h8)(_Float16)0.f;
        if (nb + row < n) hv = ((const h8*)hg)[(size_t)(nb + row) * 32 + c8];
        float* dst = &hs[row][c8 * 8];
#pragma unroll
        for (int j = 0; j < 8; ++j) dst[j] = (float)hv[j];
    }
    __syncthreads();

    int ng = t >> 4, cg = t & 15;
    int n0 = ng * 4, c0 = cg * 4;
    float acc[4][4];
#pragma unroll
    for (int a = 0; a < 4; ++a)
#pragma unroll
        for (int c = 0; c < 4; ++c) acc[a][c] = 0.f;

    for (int k = 0; k < 256; k += 4) {
        float4 w0 = *(const float4*)&wp_s[(k + 0) * 64 + c0];
        float4 w1 = *(const float4*)&wp_s[(k + 1) * 64 + c0];
        float4 w2 = *(const float4*)&wp_s[(k + 2) * 64 + c0];
        float4 w3 = *(const float4*)&wp_s[(k + 3) * 64 + c0];
#pragma unroll
        for (int a = 0; a < 4; ++a) {
            float4 hv = *(const float4*)&hs[n0 + a][k];
            acc[a][0] += hv.x * w0.x + hv.y * w1.x + hv.z * w2.x + hv.w * w3.x;
            acc[a][1] += hv.x * w0.y + hv.y * w1.y + hv.z * w2.y + hv.w * w3.y;
            acc[a][2] += hv.x * w0.z + hv.y * w1.z + hv.z * w2.z + hv.w * w3.z;
            acc[a][3] += hv.x * w0.w + hv.y * w1.w + hv.z * w2.w + hv.w * w3.w;
        }
    }

    float4 bpv = ((const float4*)bp)[cg];
    float4 gv  = ((const float4*)gamma)[cg];
    float4 bv  = ((const float4*)beta)[cg];
#pragma unroll
    for (int a = 0; a < 4; ++a) {
        int node = nb + n0 + a;
        float4 xv = make_float4(0.f, 0.f, 0.f, 0.f);
        if (node < n) xv = ((const float4*)x)[(size_t)node * 16 + cg];
        float h[4];
        h[0] = acc[a][0] + bpv.x + xv.x; h[1] = acc[a][1] + bpv.y + xv.y;
        h[2] = acc[a][2] + bpv.z + xv.z; h[3] = acc[a][3] + bpv.w + xv.w;
#pragma unroll
        for (int c = 0; c < 4; ++c) h[c] = h[c] > 0.f ? h[c] : expm1f(h[c]);
        float sum = h[0] + h[1] + h[2] + h[3];
#pragma unroll
        for (int o = 8; o >= 1; o >>= 1) sum += __shfl_xor(sum, o);
        float mu = sum * (1.f / 64.f);
        float d[4]; float s2 = 0.f;
#pragma unroll
        for (int c = 0; c < 4; ++c) { d[c] = h[c] - mu; s2 += d[c] * d[c]; }
#pragma unroll
        for (int o = 8; o >= 1; o >>= 1) s2 += __shfl_xor(s2, o);
        float r = rsqrtf(s2 * (1.f / 64.f) + LN_EPS);
        float4 ov;
        ov.x = d[0] * r * gv.x + bv.x; ov.y = d[1] * r * gv.y + bv.y;
        ov.z = d[2] * r * gv.z + bv.z; ov.w = d[3] * r * gv.w + bv.w;
        if (node < n) ((float4*)out)[(size_t)node * 16 + cg] = ov;
    }
}

// ---------------- launcher ----------------
extern "C" void kernel_launch(void* const* d_in, const int* in_sizes, int n_in,
                              void* d_out, int out_size, void* d_ws, size_t ws_size,
                              hipStream_t stream) {
    const float* x         = (const float*)d_in[0];
    const int*   ei        = (const int*)d_in[1];
    const float* ea        = (const float*)d_in[2];
    const float* Wl        = (const float*)d_in[3];
    const float* bl        = (const float*)d_in[4];
    const float* Wr        = (const float*)d_in[5];
    const float* br        = (const float*)d_in[6];
    const float* We        = (const float*)d_in[7];
    const float* att       = (const float*)d_in[8];
    const float* bias_conv = (const float*)d_in[9];
    const float* Wp        = (const float*)d_in[10];
    const float* bp        = (const float*)d_in[11];
    const float* gamma     = (const float*)d_in[12];
    const float* beta      = (const float*)d_in[13];
    float* out = (float*)d_out;

    int N = in_sizes[0] / 64;
    int E = in_sizes[2];

    char* w = (char*)d_ws;
    auto alloc = [&](size_t bytes) {
        char* p = w;
        w += (bytes + 255) & ~(size_t)255;
        return p;
    };
    _Float16* xlh     = (_Float16*)alloc((size_t)N * 256 * 2);
    _Float16* xrh     = (_Float16*)alloc((size_t)N * 256 * 2);
    _Float16* hgh     = (_Float16*)alloc((size_t)N * 256 * 2);
    int*      csr_src = (int*)    alloc((size_t)E * 4);
    float*    csr_ea  = (float*)  alloc((size_t)E * 4);
    int*      deg     = (int*)    alloc((size_t)N * 4);
    int*      off     = (int*)    alloc((size_t)(N + 1) * 4);
    int*      cursor  = (int*)    alloc((size_t)N * 4);
    float*    easum   = (float*)  alloc(4);

    init_kernel<<<(N + 255) / 256, 256, 0, stream>>>(deg, cursor, easum, N);
    transform_kernel<<<(N + 7) / 8, 256, 0, stream>>>(x, Wl, bl, Wr, br, xlh, xrh, N);
    edge_prep<<<(E + 255) / 256, 256, 0, stream>>>(ei, ea, deg, easum, E);
    scan_kernel<<<1, 256, 0, stream>>>(deg, off, N);
    fill_kernel<<<(E + 255) / 256, 256, 0, stream>>>(ei, ea, off, cursor, csr_src, csr_ea, E);
    gat_kernel<<<(N + 3) / 4, 256, 0, stream>>>(xlh, xrh, off, csr_src, csr_ea, att, We,
                                                bias_conv, easum, hgh, N, 1.f / (float)E);
    proj_ln_kernel<<<(N + 63) / 64, 256, 0, stream>>>(hgh, Wp, bp, x, gamma, beta, out, N);
}

// Round 3
// 124.170 us; speedup vs baseline: 1.9816x; 1.9816x over previous
//
#include <hip/hip_runtime.h>
#include <math.h>

typedef _Float16 h2 __attribute__((ext_vector_type(2)));
typedef _Float16 h4 __attribute__((ext_vector_type(4)));
typedef _Float16 h8 __attribute__((ext_vector_type(8)));

#define NEG_SLOPE 0.2f
#define LN_EPS 1e-5f
#define RESCALE_THR 8.0f
#define SLOT 64

#if __has_builtin(__builtin_amdgcn_fdot2)
#define FDOT2(a, b, c) __builtin_amdgcn_fdot2((a), (b), (c), false)
#else
static __device__ __forceinline__ float FDOT2(h2 a, h2 b, float c) {
    return c + (float)a[0] * (float)b[0] + (float)a[1] * (float)b[1];
}
#endif

// ---------------- K1: bucket edges into per-dst slots + per-block ea partial ----------------
__global__ __launch_bounds__(256) void fill_kernel(
    const int* __restrict__ ei, const float* __restrict__ ea,
    int* __restrict__ cursor, int2* __restrict__ rec,
    float* __restrict__ partials, int E) {
    int i = blockIdx.x * 256 + threadIdx.x;
    float s = 0.f;
    if (i < E) {
        int src = ei[i];
        int dst = ei[E + i];
        float a = ea[i];
        s = a;
        int pos = atomicAdd(&cursor[dst], 1);
        if (pos < SLOT) {
            int2 r; r.x = src; r.y = __float_as_int(a);
            rec[(size_t)dst * SLOT + pos] = r;
        }
    }
    __shared__ float red[4];
#pragma unroll
    for (int o = 32; o >= 1; o >>= 1) s += __shfl_xor(s, o);
    if ((threadIdx.x & 63) == 0) red[threadIdx.x >> 6] = s;
    __syncthreads();
    if (threadIdx.x == 0) partials[blockIdx.x] = red[0] + red[1] + red[2] + red[3];
}

// ---------------- K2: reduce partials -> ea_mean (premultiplied) ----------------
__global__ __launch_bounds__(256) void easum_reduce(const float* __restrict__ partials,
                                                    float* __restrict__ easum, int nb, float inv_e) {
    float s = 0.f;
    for (int i = threadIdx.x; i < nb; i += 256) s += partials[i];
#pragma unroll
    for (int o = 32; o >= 1; o >>= 1) s += __shfl_xor(s, o);
    __shared__ float red[4];
    if ((threadIdx.x & 63) == 0) red[threadIdx.x >> 6] = s;
    __syncthreads();
    if (threadIdx.x == 0) easum[0] = (red[0] + red[1] + red[2] + red[3]) * inv_e;
}

// ---------------- K3: x_l = x@Wl+bl, x_r = x@Wr+br -> fp16 (16 nodes/block) ----------------
__global__ __launch_bounds__(256) void transform_kernel(
    const float* __restrict__ x, const float* __restrict__ Wl, const float* __restrict__ bl,
    const float* __restrict__ Wr, const float* __restrict__ br,
    _Float16* __restrict__ xlh, _Float16* __restrict__ xrh, int n) {
    __shared__ float xs[16][64];
    int nb = blockIdx.x * 16;
    int rows = n - nb; if (rows > 16) rows = 16;
    int t = threadIdx.x;
    if (t < rows * 16) ((float4*)xs)[t] = ((const float4*)(x + (size_t)nb * 64))[t];
    __syncthreads();
    float blv = bl[t], brv = br[t];
    float accl[16], accr[16];
#pragma unroll
    for (int i = 0; i < 16; ++i) { accl[i] = blv; accr[i] = brv; }
    for (int k = 0; k < 64; k += 4) {
        float wl0 = Wl[(k + 0) * 256 + t], wl1 = Wl[(k + 1) * 256 + t];
        float wl2 = Wl[(k + 2) * 256 + t], wl3 = Wl[(k + 3) * 256 + t];
        float wr0 = Wr[(k + 0) * 256 + t], wr1 = Wr[(k + 1) * 256 + t];
        float wr2 = Wr[(k + 2) * 256 + t], wr3 = Wr[(k + 3) * 256 + t];
#pragma unroll
        for (int i = 0; i < 16; ++i) {
            float4 xv = *(const float4*)&xs[i][k];   // broadcast, conflict-free
            accl[i] += xv.x * wl0 + xv.y * wl1 + xv.z * wl2 + xv.w * wl3;
            accr[i] += xv.x * wr0 + xv.y * wr1 + xv.z * wr2 + xv.w * wr3;
        }
    }
    for (int i = 0; i < rows; ++i) {
        xlh[(size_t)(nb + i) * 256 + t] = (_Float16)accl[i];
        xrh[(size_t)(nb + i) * 256 + t] = (_Float16)accr[i];
    }
}

// ---------------- K4: per-node GATv2, two edges in flight (half-wave each) ----------------
__global__ __launch_bounds__(256) void gat_kernel(
    const _Float16* __restrict__ xlh, const _Float16* __restrict__ xrh,
    const int* __restrict__ cursor, const int2* __restrict__ rec,
    const float* __restrict__ att, const float* __restrict__ We, const float* __restrict__ bias_conv,
    const float* __restrict__ easum, _Float16* __restrict__ hg, int n) {
    int wid = (blockIdx.x * blockDim.x + threadIdx.x) >> 6;
    if (wid >= n) return;
    int lane = threadIdx.x & 63;
    int half = lane >> 5, s = lane & 31;      // lane covers dims 8s..8s+7
    float ea_mean = easum[0];

    h8 xrv = ((const h8*)xrh)[(size_t)wid * 32 + s];
    h2 xr2[4], we2[4], c02 = {(_Float16)NEG_SLOPE, (_Float16)NEG_SLOPE};
    float atf[8];
    const float* attp = att + 8 * s;
    const float* wep = We + 8 * s;
#pragma unroll
    for (int j = 0; j < 4; ++j) {
        xr2[j] = (h2){xrv[2 * j], xrv[2 * j + 1]};
        we2[j] = (h2){(_Float16)wep[2 * j], (_Float16)wep[2 * j + 1]};
        atf[2 * j] = attp[2 * j]; atf[2 * j + 1] = attp[2 * j + 1];
    }
    const h8* xl8 = (const h8*)xlh;
    const int2* myrec = rec + (size_t)wid * SLOT;

    float M = -1e30f, S = 0.f, acc[8];
#pragma unroll
    for (int j = 0; j < 8; ++j) acc[j] = 0.f;
    int cnt = cursor[wid]; if (cnt > SLOT) cnt = SLOT;
    int total = cnt + 1;                      // +1 = self loop at i==0

    auto edge_compute = [&](int i, float* vf) -> float {
        int src; float a;
        if (i == 0) { src = wid; a = ea_mean; }
        else        { int2 r = myrec[i - 1]; src = r.x; a = __int_as_float(r.y); }
        h8 v = xl8[(size_t)src * 32 + s];
        _Float16 ah = (_Float16)a;
        h2 aa = {ah, ah};
        float p = 0.f;
#pragma unroll
        for (int j = 0; j < 4; ++j) {
            h2 vj = (h2){v[2 * j], v[2 * j + 1]};
            h2 m = aa * we2[j] + (vj + xr2[j]);
            h2 l = __builtin_elementwise_max(m, m * c02);   // leaky relu
            p += (float)l[0] * atf[2 * j] + (float)l[1] * atf[2 * j + 1];
            vf[2 * j] = (float)vj[0]; vf[2 * j + 1] = (float)vj[1];
        }
        p += __shfl_xor(p, 1);
        p += __shfl_xor(p, 2);
        p += __shfl_xor(p, 4);
        return p;
    };

    int i = half;
    if (i < total) {
        float vf[8];
        float p = edge_compute(i, vf);
        M = p; S = 1.f;
#pragma unroll
        for (int j = 0; j < 8; ++j) acc[j] = vf[j];
        i += 2;
    }
    for (; i < total; i += 2) {
        float vf[8];
        float p = edge_compute(i, vf);
        if (__all(p <= M + RESCALE_THR)) {     // defer-max fast path
            float w = __expf(p - M);
            S += w;
#pragma unroll
            for (int j = 0; j < 8; ++j) acc[j] += w * vf[j];
        } else {
            float newM = fmaxf(M, p);
            float sc = __expf(M - newM), w = __expf(p - newM);
            S = S * sc + w;
#pragma unroll
            for (int j = 0; j < 8; ++j) acc[j] = acc[j] * sc + w * vf[j];
            M = newM;
        }
    }

    // merge the two half-wave softmax states
    float Mo = __shfl_xor(M, 32);
    float newM = fmaxf(M, Mo);
    float sc = __expf(M - newM);
    S *= sc;
    S += __shfl_xor(S, 32);
#pragma unroll
    for (int j = 0; j < 8; ++j) { acc[j] *= sc; acc[j] += __shfl_xor(acc[j], 32); }
    float inv = 1.f / (S + 1e-16f);

    float4 bc = ((const float4*)bias_conv)[2 * s + half];
    const float* ap = acc + 4 * half;
    h4 ov = {(_Float16)(ap[0] * inv + bc.x), (_Float16)(ap[1] * inv + bc.y),
             (_Float16)(ap[2] * inv + bc.z), (_Float16)(ap[3] * inv + bc.w)};
    ((h4*)hg)[(size_t)wid * 64 + 2 * s + half] = ov;
}

// ---------------- K5: proj(256->64) + residual + ELU + LN (fp16 LDS, dot2 accum) ----------------
__global__ __launch_bounds__(256) void proj_ln_kernel(
    const _Float16* __restrict__ hg, const float* __restrict__ Wp, const float* __restrict__ bp,
    const float* __restrict__ x, const float* __restrict__ gamma, const float* __restrict__ beta,
    float* __restrict__ out, int n) {
    __shared__ _Float16 wp_t[64 * 256];   // transposed [c][k], XOR-swizzled; 32 KB
    __shared__ _Float16 hs[64][264];      // [node][k], +8 pad; 33 KB
    int t = threadIdx.x;
    int nb = blockIdx.x * 64;
    // stage Wp: read row-major f32, write transposed fp16 with chunk swizzle
    for (int idx = t; idx < 4096; idx += 256) {
        float4 wv = ((const float4*)Wp)[idx];
        int k = idx >> 4, c0s = (idx & 15) * 4;
#pragma unroll
        for (int m = 0; m < 4; ++m) {
            int c = c0s + m;
            int off = c * 256 + ((((k >> 3) ^ ((c >> 2) & 7)) << 3) | (k & 7));
            wp_t[off] = (_Float16)((&wv.x)[m]);
        }
    }
    for (int idx = t; idx < 2048; idx += 256) {
        int row = idx >> 5, c8 = idx & 31;
        h8 hv = (h8)(_Float16)0.f;
        if (nb + row < n) hv = ((const h8*)hg)[(size_t)(nb + row) * 32 + c8];
        *(h8*)&hs[row][c8 * 8] = hv;
    }
    __syncthreads();

    int ng = t >> 4, cg = t & 15;
    int n0 = ng * 4, c0 = cg * 4;
    float acc[4][4];
#pragma unroll
    for (int a = 0; a < 4; ++a)
#pragma unroll
        for (int c = 0; c < 4; ++c) acc[a][c] = 0.f;

    for (int k = 0; k < 256; k += 8) {
        h8 hr[4], wr_[4];
#pragma unroll
        for (int a = 0; a < 4; ++a) hr[a] = *(const h8*)&hs[n0 + a][k];
#pragma unroll
        for (int j = 0; j < 4; ++j) {
            int c = c0 + j;
            int off = c * 256 + (((k >> 3) ^ ((c >> 2) & 7)) << 3);
            wr_[j] = *(const h8*)&wp_t[off];
        }
#pragma unroll
        for (int a = 0; a < 4; ++a) {
            const h2* hp = (const h2*)&hr[a];
#pragma unroll
            for (int j = 0; j < 4; ++j) {
                const h2* wp2 = (const h2*)&wr_[j];
                acc[a][j] = FDOT2(hp[0], wp2[0], acc[a][j]);
                acc[a][j] = FDOT2(hp[1], wp2[1], acc[a][j]);
                acc[a][j] = FDOT2(hp[2], wp2[2], acc[a][j]);
                acc[a][j] = FDOT2(hp[3], wp2[3], acc[a][j]);
            }
        }
    }

    float4 bpv = ((const float4*)bp)[cg];
    float4 gv  = ((const float4*)gamma)[cg];
    float4 bv  = ((const float4*)beta)[cg];
#pragma unroll
    for (int a = 0; a < 4; ++a) {
        int node = nb + n0 + a;
        float4 xv = make_float4(0.f, 0.f, 0.f, 0.f);
        if (node < n) xv = ((const float4*)x)[(size_t)node * 16 + cg];
        float h[4];
        h[0] = acc[a][0] + bpv.x + xv.x; h[1] = acc[a][1] + bpv.y + xv.y;
        h[2] = acc[a][2] + bpv.z + xv.z; h[3] = acc[a][3] + bpv.w + xv.w;
#pragma unroll
        for (int c = 0; c < 4; ++c) h[c] = h[c] > 0.f ? h[c] : expm1f(h[c]);
        float sum = h[0] + h[1] + h[2] + h[3];
#pragma unroll
        for (int o = 8; o >= 1; o >>= 1) sum += __shfl_xor(sum, o);
        float mu = sum * (1.f / 64.f);
        float d[4]; float s2 = 0.f;
#pragma unroll
        for (int c = 0; c < 4; ++c) { d[c] = h[c] - mu; s2 += d[c] * d[c]; }
#pragma unroll
        for (int o = 8; o >= 1; o >>= 1) s2 += __shfl_xor(s2, o);
        float r = rsqrtf(s2 * (1.f / 64.f) + LN_EPS);
        float4 ov;
        ov.x = d[0] * r * gv.x + bv.x; ov.y = d[1] * r * gv.y + bv.y;
        ov.z = d[2] * r * gv.z + bv.z; ov.w = d[3] * r * gv.w + bv.w;
        if (node < n) ((float4*)out)[(size_t)node * 16 + cg] = ov;
    }
}

// ---------------- launcher ----------------
extern "C" void kernel_launch(void* const* d_in, const int* in_sizes, int n_in,
                              void* d_out, int out_size, void* d_ws, size_t ws_size,
                              hipStream_t stream) {
    const float* x         = (const float*)d_in[0];
    const int*   ei        = (const int*)d_in[1];
    const float* ea        = (const float*)d_in[2];
    const float* Wl        = (const float*)d_in[3];
    const float* bl        = (const float*)d_in[4];
    const float* Wr        = (const float*)d_in[5];
    const float* br        = (const float*)d_in[6];
    const float* We        = (const float*)d_in[7];
    const float* att       = (const float*)d_in[8];
    const float* bias_conv = (const float*)d_in[9];
    const float* Wp        = (const float*)d_in[10];
    const float* bp        = (const float*)d_in[11];
    const float* gamma     = (const float*)d_in[12];
    const float* beta      = (const float*)d_in[13];
    float* out = (float*)d_out;

    int N = in_sizes[0] / 64;
    int E = in_sizes[2];
    int EB = (E + 255) / 256;   // fill blocks = partials count

    char* w = (char*)d_ws;
    auto alloc = [&](size_t bytes) {
        char* p = w;
        w += (bytes + 255) & ~(size_t)255;
        return p;
    };
    _Float16* xlh     = (_Float16*)alloc((size_t)N * 256 * 2);
    _Float16* xrh     = (_Float16*)alloc((size_t)N * 256 * 2);
    _Float16* hgh     = (_Float16*)alloc((size_t)N * 256 * 2);
    int2*     rec     = (int2*)   alloc((size_t)N * SLOT * 8);
    char*     zbase   = w;
    int*      cursor  = (int*)    alloc((size_t)N * 4);
    float*    partials= (float*)  alloc((size_t)EB * 4);
    float*    easum   = (float*)  alloc(4);
    size_t    zlen    = (size_t)(w - zbase);

    hipMemsetAsync(zbase, 0, zlen, stream);   // cursor + partials + easum

    fill_kernel<<<EB, 256, 0, stream>>>(ei, ea, cursor, rec, partials, E);
    easum_reduce<<<1, 256, 0, stream>>>(partials, easum, EB, 1.f / (float)E);
    transform_kernel<<<(N + 15) / 16, 256, 0, stream>>>(x, Wl, bl, Wr, br, xlh, xrh, N);
    gat_kernel<<<(N + 3) / 4, 256, 0, stream>>>(xlh, xrh, cursor, rec, att, We,
                                                bias_conv, easum, hgh, N);
    proj_ln_kernel<<<(N + 63) / 64, 256, 0, stream>>>(hgh, Wp, bp, x, gamma, beta, out, N);
}

// Round 4
// 123.135 us; speedup vs baseline: 1.9983x; 1.0084x over previous
//
#include <hip/hip_runtime.h>
#include <math.h>

typedef _Float16 h2 __attribute__((ext_vector_type(2)));
typedef _Float16 h4 __attribute__((ext_vector_type(4)));
typedef _Float16 h8 __attribute__((ext_vector_type(8)));

#define NEG_SLOPE 0.2f
#define LN_EPS 1e-5f
#define RESCALE_THR 8.0f
#define SLOT 64

#if __has_builtin(__builtin_amdgcn_fdot2)
#define FDOT2(a, b, c) __builtin_amdgcn_fdot2((a), (b), (c), false)
#else
static __device__ __forceinline__ float FDOT2(h2 a, h2 b, float c) {
    return c + (float)a[0] * (float)b[0] + (float)a[1] * (float)b[1];
}
#endif

// sum over the 8-lane head group (lane bits 0..2) with pure-VALU DPP ops
static __device__ __forceinline__ float red8_dpp(float p) {
    p += __int_as_float(__builtin_amdgcn_mov_dpp(__float_as_int(p), 0xB1, 0xF, 0xF, true));  // quad_perm xor1
    p += __int_as_float(__builtin_amdgcn_mov_dpp(__float_as_int(p), 0x4E, 0xF, 0xF, true));  // quad_perm xor2
    p += __int_as_float(__builtin_amdgcn_mov_dpp(__float_as_int(p), 0x141, 0xF, 0xF, true)); // row_half_mirror
    return p;
}

// ---------------- K0: zero cursor / partials / easum ----------------
__global__ void init_kernel(int* __restrict__ cursor, float* __restrict__ partials,
                            float* __restrict__ easum, int n, int eb) {
    int i = blockIdx.x * 256 + threadIdx.x;
    if (i < n) cursor[i] = 0;
    if (i < eb) partials[i] = 0.f;
    if (i == 0) easum[0] = 0.f;
}

// ---------------- K1: bucket edges into per-dst slots + per-block ea partial ----------------
__global__ __launch_bounds__(256) void fill_kernel(
    const int* __restrict__ ei, const float* __restrict__ ea,
    int* __restrict__ cursor, int2* __restrict__ rec,
    float* __restrict__ partials, int E) {
    int i = blockIdx.x * 256 + threadIdx.x;
    float s = 0.f;
    if (i < E) {
        int src = ei[i];
        int dst = ei[E + i];
        float a = ea[i];
        s = a;
        int pos = atomicAdd(&cursor[dst], 1);
        if (pos < SLOT) {
            int2 r; r.x = src; r.y = __float_as_int(a);
            rec[(size_t)dst * SLOT + pos] = r;
        }
    }
    __shared__ float red[4];
#pragma unroll
    for (int o = 32; o >= 1; o >>= 1) s += __shfl_xor(s, o);
    if ((threadIdx.x & 63) == 0) red[threadIdx.x >> 6] = s;
    __syncthreads();
    if (threadIdx.x == 0) partials[blockIdx.x] = red[0] + red[1] + red[2] + red[3];
}

// ---------------- K2: transforms -> fp16, + block 0 reduces ea partials ----------------
__global__ __launch_bounds__(256) void transform_kernel(
    const float* __restrict__ x, const float* __restrict__ Wl, const float* __restrict__ bl,
    const float* __restrict__ Wr, const float* __restrict__ br,
    _Float16* __restrict__ xlh, _Float16* __restrict__ xrh,
    const float* __restrict__ partials, float* __restrict__ easum,
    int n, int eb, float inv_e) {
    __shared__ float xs[16][64];
    int nb = blockIdx.x * 16;
    int rows = n - nb; if (rows > 16) rows = 16;
    int t = threadIdx.x;
    if (t < rows * 16) ((float4*)xs)[t] = ((const float4*)(x + (size_t)nb * 64))[t];
    __syncthreads();
    float blv = bl[t], brv = br[t];
    float accl[16], accr[16];
#pragma unroll
    for (int i = 0; i < 16; ++i) { accl[i] = blv; accr[i] = brv; }
    for (int k = 0; k < 64; k += 4) {
        float wl0 = Wl[(k + 0) * 256 + t], wl1 = Wl[(k + 1) * 256 + t];
        float wl2 = Wl[(k + 2) * 256 + t], wl3 = Wl[(k + 3) * 256 + t];
        float wr0 = Wr[(k + 0) * 256 + t], wr1 = Wr[(k + 1) * 256 + t];
        float wr2 = Wr[(k + 2) * 256 + t], wr3 = Wr[(k + 3) * 256 + t];
#pragma unroll
        for (int i = 0; i < 16; ++i) {
            float4 xv = *(const float4*)&xs[i][k];   // broadcast, conflict-free
            accl[i] += xv.x * wl0 + xv.y * wl1 + xv.z * wl2 + xv.w * wl3;
            accr[i] += xv.x * wr0 + xv.y * wr1 + xv.z * wr2 + xv.w * wr3;
        }
    }
    for (int i = 0; i < rows; ++i) {
        xlh[(size_t)(nb + i) * 256 + t] = (_Float16)accl[i];
        xrh[(size_t)(nb + i) * 256 + t] = (_Float16)accr[i];
    }
    if (blockIdx.x == 0) {   // fold the easum reduction in (fill ran before us)
        float s = 0.f;
        for (int i = t; i < eb; i += 256) s += partials[i];
#pragma unroll
        for (int o = 32; o >= 1; o >>= 1) s += __shfl_xor(s, o);
        __shared__ float red[4];
        if ((t & 63) == 0) red[t >> 6] = s;
        __syncthreads();
        if (t == 0) easum[0] = (red[0] + red[1] + red[2] + red[3]) * inv_e;
    }
}

// ---------------- K3: per-node GATv2, 2 edges/half-wave in flight ----------------
__global__ __launch_bounds__(256) void gat_kernel(
    const _Float16* __restrict__ xlh, const _Float16* __restrict__ xrh,
    const int* __restrict__ cursor, const int2* __restrict__ rec,
    const float* __restrict__ att, const float* __restrict__ We, const float* __restrict__ bias_conv,
    const float* __restrict__ easum, _Float16* __restrict__ hg, int n) {
    int wid = (blockIdx.x * blockDim.x + threadIdx.x) >> 6;
    if (wid >= n) return;
    int lane = threadIdx.x & 63;
    int half = lane >> 5, s = lane & 31;      // lane covers dims 8s..8s+7

    h8 xrv = ((const h8*)xrh)[(size_t)wid * 32 + s];
    h2 xr2[4], we2[4], c02 = {(_Float16)NEG_SLOPE, (_Float16)NEG_SLOPE};
    float atf[8];
    const float* attp = att + 8 * s;
    const float* wep = We + 8 * s;
#pragma unroll
    for (int j = 0; j < 4; ++j) {
        xr2[j] = (h2){xrv[2 * j], xrv[2 * j + 1]};
        we2[j] = (h2){(_Float16)wep[2 * j], (_Float16)wep[2 * j + 1]};
        atf[2 * j] = attp[2 * j]; atf[2 * j + 1] = attp[2 * j + 1];
    }
    const h8* xl8 = (const h8*)xlh;
    const int2* myrec = rec + (size_t)wid * SLOT;

    auto edge_p = [&](h8 v, float a) -> float {
        _Float16 ah = (_Float16)a;
        h2 a2 = {ah, ah};
        float p = 0.f;
#pragma unroll
        for (int j = 0; j < 4; ++j) {
            h2 vj = (h2){v[2 * j], v[2 * j + 1]};
            h2 m = a2 * we2[j] + (vj + xr2[j]);
            h2 l = __builtin_elementwise_max(m, m * c02);   // leaky relu
            p = fmaf((float)l[0], atf[2 * j], p);
            p = fmaf((float)l[1], atf[2 * j + 1], p);
        }
        return red8_dpp(p);
    };

    float M = -1e30f, S = 0.f, acc[8];
#pragma unroll
    for (int j = 0; j < 8; ++j) acc[j] = 0.f;
    int cnt = cursor[wid]; if (cnt > SLOT) cnt = SLOT;
    int total = cnt + 1;                      // edge list = [self] + rec[0..cnt)

    auto online = [&](float p, h8 v) {
        float newM = fmaxf(M, p);
        float sc = __expf(M - newM), w = __expf(p - newM);
        S = S * sc + w;
#pragma unroll
        for (int j = 0; j < 8; ++j) acc[j] = fmaf(acc[j], sc, w * (float)v[j]);
        M = newM;
    };

    // prologue: half 0 takes the self loop, half 1 takes rec[0] (if any)
    int i = half;
    {
        int src = wid; float a = easum[0];
        bool has = (i < total);
        if (half == 1 && has) { int2 r = myrec[0]; src = r.x; a = __int_as_float(r.y); }
        h8 v = xl8[(size_t)src * 32 + s];
        float p = edge_p(v, a);
        if (has) {
            M = p; S = 1.f;
#pragma unroll
            for (int j = 0; j < 8; ++j) acc[j] = (float)v[j];
            i += 2;
        }
    }
    // pair loop: edges i and i+2 of this half in flight together
    for (; i + 2 < total; i += 4) {
        int2 r0 = myrec[i - 1], r1 = myrec[i + 1];
        h8 v0 = xl8[(size_t)r0.x * 32 + s];
        h8 v1 = xl8[(size_t)r1.x * 32 + s];
        float p0 = edge_p(v0, __int_as_float(r0.y));
        float p1 = edge_p(v1, __int_as_float(r1.y));
        if (__all(fmaxf(p0, p1) <= M + RESCALE_THR)) {   // defer-max fast path
            float w0 = __expf(p0 - M), w1 = __expf(p1 - M);
            S += w0 + w1;
#pragma unroll
            for (int j = 0; j < 8; ++j) {
                acc[j] = fmaf((float)v0[j], w0, acc[j]);
                acc[j] = fmaf((float)v1[j], w1, acc[j]);
            }
        } else {
            online(p0, v0);
            online(p1, v1);
        }
    }
    if (i < total) {   // tail single edge
        int2 r = myrec[i - 1];
        h8 v = xl8[(size_t)r.x * 32 + s];
        float p = edge_p(v, __int_as_float(r.y));
        online(p, v);
    }

    // merge the two half-wave softmax states
    float Mo = __shfl_xor(M, 32);
    float newM = fmaxf(M, Mo);
    float sc = __expf(M - newM);
    S *= sc;
    S += __shfl_xor(S, 32);
#pragma unroll
    for (int j = 0; j < 8; ++j) { acc[j] *= sc; acc[j] += __shfl_xor(acc[j], 32); }
    float inv = 1.f / (S + 1e-16f);

    float4 bc = ((const float4*)bias_conv)[2 * s + half];
    const float* ap = acc + 4 * half;
    h4 ov = {(_Float16)(ap[0] * inv + bc.x), (_Float16)(ap[1] * inv + bc.y),
             (_Float16)(ap[2] * inv + bc.z), (_Float16)(ap[3] * inv + bc.w)};
    ((h4*)hg)[(size_t)wid * 64 + 2 * s + half] = ov;
}

// ---------------- K4: proj(256->64) + residual + ELU + LN (fp16 LDS, dot2) ----------------
__global__ __launch_bounds__(256) void proj_ln_kernel(
    const _Float16* __restrict__ hg, const float* __restrict__ Wp, const float* __restrict__ bp,
    const float* __restrict__ x, const float* __restrict__ gamma, const float* __restrict__ beta,
    float* __restrict__ out, int n) {
    __shared__ _Float16 wp_t[64 * 256];   // transposed [c][k], XOR-swizzled; 32 KB
    __shared__ _Float16 hs[64][264];      // [node][k], +8 pad; 33 KB
    int t = threadIdx.x;
    int nb = blockIdx.x * 64;
    for (int idx = t; idx < 4096; idx += 256) {
        float4 wv = ((const float4*)Wp)[idx];
        int k = idx >> 4, c0s = (idx & 15) * 4;
#pragma unroll
        for (int m = 0; m < 4; ++m) {
            int c = c0s + m;
            int off = c * 256 + ((((k >> 3) ^ ((c >> 2) & 7)) << 3) | (k & 7));
            wp_t[off] = (_Float16)((&wv.x)[m]);
        }
    }
    for (int idx = t; idx < 2048; idx += 256) {
        int row = idx >> 5, c8 = idx & 31;
        h8 hv = (h8)(_Float16)0.f;
        if (nb + row < n) hv = ((const h8*)hg)[(size_t)(nb + row) * 32 + c8];
        *(h8*)&hs[row][c8 * 8] = hv;
    }
    __syncthreads();

    int ng = t >> 4, cg = t & 15;
    int n0 = ng * 4, c0 = cg * 4;
    float acc[4][4];
#pragma unroll
    for (int a = 0; a < 4; ++a)
#pragma unroll
        for (int c = 0; c < 4; ++c) acc[a][c] = 0.f;

    for (int k = 0; k < 256; k += 8) {
        h8 hr[4], wr_[4];
#pragma unroll
        for (int a = 0; a < 4; ++a) hr[a] = *(const h8*)&hs[n0 + a][k];
#pragma unroll
        for (int j = 0; j < 4; ++j) {
            int c = c0 + j;
            int off = c * 256 + (((k >> 3) ^ ((c >> 2) & 7)) << 3);
            wr_[j] = *(const h8*)&wp_t[off];
        }
#pragma unroll
        for (int a = 0; a < 4; ++a) {
            const h2* hp = (const h2*)&hr[a];
#pragma unroll
            for (int j = 0; j < 4; ++j) {
                const h2* wp2 = (const h2*)&wr_[j];
                acc[a][j] = FDOT2(hp[0], wp2[0], acc[a][j]);
                acc[a][j] = FDOT2(hp[1], wp2[1], acc[a][j]);
                acc[a][j] = FDOT2(hp[2], wp2[2], acc[a][j]);
                acc[a][j] = FDOT2(hp[3], wp2[3], acc[a][j]);
            }
        }
    }

    float4 bpv = ((const float4*)bp)[cg];
    float4 gv  = ((const float4*)gamma)[cg];
    float4 bv  = ((const float4*)beta)[cg];
#pragma unroll
    for (int a = 0; a < 4; ++a) {
        int node = nb + n0 + a;
        float4 xv = make_float4(0.f, 0.f, 0.f, 0.f);
        if (node < n) xv = ((const float4*)x)[(size_t)node * 16 + cg];
        float h[4];
        h[0] = acc[a][0] + bpv.x + xv.x; h[1] = acc[a][1] + bpv.y + xv.y;
        h[2] = acc[a][2] + bpv.z + xv.z; h[3] = acc[a][3] + bpv.w + xv.w;
#pragma unroll
        for (int c = 0; c < 4; ++c) h[c] = h[c] > 0.f ? h[c] : expm1f(h[c]);
        float sum = h[0] + h[1] + h[2] + h[3];
#pragma unroll
        for (int o = 8; o >= 1; o >>= 1) sum += __shfl_xor(sum, o);
        float mu = sum * (1.f / 64.f);
        float d[4]; float s2 = 0.f;
#pragma unroll
        for (int c = 0; c < 4; ++c) { d[c] = h[c] - mu; s2 += d[c] * d[c]; }
#pragma unroll
        for (int o = 8; o >= 1; o >>= 1) s2 += __shfl_xor(s2, o);
        float r = rsqrtf(s2 * (1.f / 64.f) + LN_EPS);
        float4 ov;
        ov.x = d[0] * r * gv.x + bv.x; ov.y = d[1] * r * gv.y + bv.y;
        ov.z = d[2] * r * gv.z + bv.z; ov.w = d[3] * r * gv.w + bv.w;
        if (node < n) ((float4*)out)[(size_t)node * 16 + cg] = ov;
    }
}

// ---------------- launcher ----------------
extern "C" void kernel_launch(void* const* d_in, const int* in_sizes, int n_in,
                              void* d_out, int out_size, void* d_ws, size_t ws_size,
                              hipStream_t stream) {
    const float* x         = (const float*)d_in[0];
    const int*   ei        = (const int*)d_in[1];
    const float* ea        = (const float*)d_in[2];
    const float* Wl        = (const float*)d_in[3];
    const float* bl        = (const float*)d_in[4];
    const float* Wr        = (const float*)d_in[5];
    const float* br        = (const float*)d_in[6];
    const float* We        = (const float*)d_in[7];
    const float* att       = (const float*)d_in[8];
    const float* bias_conv = (const float*)d_in[9];
    const float* Wp        = (const float*)d_in[10];
    const float* bp        = (const float*)d_in[11];
    const float* gamma     = (const float*)d_in[12];
    const float* beta      = (const float*)d_in[13];
    float* out = (float*)d_out;

    int N = in_sizes[0] / 64;
    int E = in_sizes[2];
    int EB = (E + 255) / 256;

    char* w = (char*)d_ws;
    auto alloc = [&](size_t bytes) {
        char* p = w;
        w += (bytes + 255) & ~(size_t)255;
        return p;
    };
    _Float16* xlh     = (_Float16*)alloc((size_t)N * 256 * 2);
    _Float16* xrh     = (_Float16*)alloc((size_t)N * 256 * 2);
    _Float16* hgh     = (_Float16*)alloc((size_t)N * 256 * 2);
    int2*     rec     = (int2*)   alloc((size_t)N * SLOT * 8);
    int*      cursor  = (int*)    alloc((size_t)N * 4);
    float*    partials= (float*)  alloc((size_t)EB * 4);
    float*    easum   = (float*)  alloc(4);

    init_kernel<<<(N + 255) / 256, 256, 0, stream>>>(cursor, partials, easum, N, EB);
    fill_kernel<<<EB, 256, 0, stream>>>(ei, ea, cursor, rec, partials, E);
    transform_kernel<<<(N + 15) / 16, 256, 0, stream>>>(x, Wl, bl, Wr, br, xlh, xrh,
                                                        partials, easum, N, EB, 1.f / (float)E);
    gat_kernel<<<(N + 3) / 4, 256, 0, stream>>>(xlh, xrh, cursor, rec, att, We,
                                                bias_conv, easum, hgh, N);
    proj_ln_kernel<<<(N + 63) / 64, 256, 0, stream>>>(hgh, Wp, bp, x, gamma, beta, out, N);
}